// Round 4
// baseline (851.900 us; speedup 1.0000x reference)
//
#include <hip/hip_runtime.h>
#include <math.h>

#define QK_SCALE 0.14433756729740643f   // 1/sqrt(3*16)
#define BB_SCALE 0.57735026918962576f   // 1/sqrt(3)
#define HW_COEF  0.13608276348795434f   // 1/sqrt(54)

// ---------------------------------------------------------------------------
// K_PROJ: tiled GEMM (1024x384)@(384x1152 composite) with scatter epilogue.
// ---------------------------------------------------------------------------
__global__ __launch_bounds__(256) void k_proj(
    const float* __restrict__ s,
    const float* __restrict__ wq,  const float* __restrict__ bq,
    const float* __restrict__ wkv, const float* __restrict__ bkv,
    const float* __restrict__ wqp, const float* __restrict__ bqp,
    const float* __restrict__ wkvp,const float* __restrict__ bkvp,
    float* __restrict__ q_o,    // (B,N,192)
    float* __restrict__ kT2,    // (B,12,512,16)
    float* __restrict__ vT,     // (B,12,16,512)
    float* __restrict__ qpl,    // (B,N,48,3) local
    float* __restrict__ kvpl)   // (B,N,144,3) local
{
    __shared__ __align__(16) float A_t[64 * 36];
    __shared__ __align__(16) float W_s[64 * 132];
    const int row0 = blockIdx.x * 32;
    const int C0 = blockIdx.y * 128;
    const int t = threadIdx.x;
    const int cq = t & 31, rq = t >> 5;
    float acc[4][4] = {};
    for (int ch = 0; ch < 6; ++ch) {
        const int k0 = ch * 64;
        __syncthreads();
        for (int idx = t; idx < 512; idx += 256) {
            int r = idx & 31, kq = idx >> 5;
            float4 a = *(const float4*)&s[(size_t)(row0 + r) * 384 + k0 + kq * 4];
            A_t[(kq * 4 + 0) * 36 + r] = a.x;
            A_t[(kq * 4 + 1) * 36 + r] = a.y;
            A_t[(kq * 4 + 2) * 36 + r] = a.z;
            A_t[(kq * 4 + 3) * 36 + r] = a.w;
        }
        for (int idx = t; idx < 2048; idx += 256) {
            int kk = idx >> 5, c4 = idx & 31;
            int C4 = C0 + c4 * 4;
            const float* w; int sub, wcols;
            if (C4 < 192)      { w = wq;   sub = C4;       wcols = 192; }
            else if (C4 < 576) { w = wkv;  sub = C4 - 192; wcols = 384; }
            else if (C4 < 720) { w = wqp;  sub = C4 - 576; wcols = 144; }
            else               { w = wkvp; sub = C4 - 720; wcols = 432; }
            *(float4*)&W_s[kk * 132 + c4 * 4] =
                *(const float4*)&w[(size_t)(k0 + kk) * wcols + sub];
        }
        __syncthreads();
        #pragma unroll 8
        for (int kk = 0; kk < 64; ++kk) {
            float4 a4 = *(const float4*)&A_t[kk * 36 + rq * 4];
            float4 w4 = *(const float4*)&W_s[kk * 132 + cq * 4];
            acc[0][0] += a4.x * w4.x; acc[0][1] += a4.x * w4.y; acc[0][2] += a4.x * w4.z; acc[0][3] += a4.x * w4.w;
            acc[1][0] += a4.y * w4.x; acc[1][1] += a4.y * w4.y; acc[1][2] += a4.y * w4.z; acc[1][3] += a4.y * w4.w;
            acc[2][0] += a4.z * w4.x; acc[2][1] += a4.z * w4.y; acc[2][2] += a4.z * w4.z; acc[2][3] += a4.z * w4.w;
            acc[3][0] += a4.w * w4.x; acc[3][1] += a4.w * w4.y; acc[3][2] += a4.w * w4.z; acc[3][3] += a4.w * w4.w;
        }
    }
    #pragma unroll
    for (int r = 0; r < 4; ++r) {
        int row = row0 + rq * 4 + r;
        int b = row >> 9, n = row & 511;
        #pragma unroll
        for (int u = 0; u < 4; ++u) {
            int col = C0 + cq * 4 + u;
            float v = acc[r][u];
            if (col < 192) {
                q_o[(size_t)row * 192 + col] = v + bq[col];
            } else if (col < 576) {
                int sub = col - 192;
                v += bkv[sub];
                int h = sub >> 5, rr = sub & 31;
                if (rr < 16) kT2[((size_t)((b * 12 + h) << 9) + n) * 16 + rr] = v;
                else         vT[(((b * 12 + h) * 16 + (rr - 16)) << 9) + n] = v;
            } else if (col < 720) {
                int sub = col - 576;
                v += bqp[sub];
                int axis = sub / 48, rem = sub % 48;
                qpl[(size_t)row * 144 + rem * 3 + axis] = v;
            } else {
                int sub = col - 720;
                v += bkvp[sub];
                int axis = sub / 144, rem = sub % 144;
                kvpl[(size_t)row * 432 + rem * 3 + axis] = v;
            }
        }
    }
}

// ---------------------------------------------------------------------------
// K_PTS: local->global point transform + scatter
// ---------------------------------------------------------------------------
__global__ __launch_bounds__(192) void k_pts(
    const float* __restrict__ qpl, const float* __restrict__ kvpl,
    const float* __restrict__ t_rot, const float* __restrict__ t_trans,
    float* __restrict__ qpg,    // (B,N,144)
    float* __restrict__ kpT2,   // (B,12,512,12)
    float* __restrict__ vptsT)  // (B,12,24,512)
{
    const int row = blockIdx.x;
    const int b = row >> 9, n = row & 511;
    const int t = threadIdx.x;
    __shared__ float R[9], T[3];
    if (t < 9) R[t] = t_rot[(size_t)row * 9 + t];
    if (t < 3) T[t] = t_trans[(size_t)row * 3 + t];
    __syncthreads();
    float lx, ly, lz;
    if (t < 48) {
        lx = qpl[(size_t)row * 144 + t * 3 + 0];
        ly = qpl[(size_t)row * 144 + t * 3 + 1];
        lz = qpl[(size_t)row * 144 + t * 3 + 2];
    } else {
        int pp = t - 48;
        lx = kvpl[(size_t)row * 432 + pp * 3 + 0];
        ly = kvpl[(size_t)row * 432 + pp * 3 + 1];
        lz = kvpl[(size_t)row * 432 + pp * 3 + 2];
    }
    float gx = R[0] * lx + R[1] * ly + R[2] * lz + T[0];
    float gy = R[3] * lx + R[4] * ly + R[5] * lz + T[1];
    float gz = R[6] * lx + R[7] * ly + R[8] * lz + T[2];
    if (t < 48) {
        qpg[(size_t)row * 144 + t * 3 + 0] = gx;
        qpg[(size_t)row * 144 + t * 3 + 1] = gy;
        qpg[(size_t)row * 144 + t * 3 + 2] = gz;
    } else {
        int pp = t - 48;
        int h = pp / 12, pt = pp % 12;
        if (pt < 4) {
            size_t base = ((size_t)((b * 12 + h) << 9) + n) * 12 + pt * 3;
            kpT2[base + 0] = gx; kpT2[base + 1] = gy; kpT2[base + 2] = gz;
        } else {
            int base = (((b * 12 + h) * 24 + (pt - 4) * 3) << 9) + n;
            vptsT[base] = gx; vptsT[base + 512] = gy; vptsT[base + 1024] = gz;
        }
    }
}

// ---------------------------------------------------------------------------
// K_LOGITS: l[b,h,i,j] = qk*scale + pt_att + BB*(bpb + p@wb) + mask.
// Grid = 4096 (row * 4 + jchunk). 256 threads. p streamed once, register
// window prefetch depth 4, p@wb reduced fully in-wave (xor 1,2,4,8).
// ---------------------------------------------------------------------------
__global__ __launch_bounds__(256, 4) void k_logits(
    const float* __restrict__ q_o,   // (B,N,192)
    const float* __restrict__ kT2,   // (B,12,512,16)
    const float* __restrict__ qpg,   // (B,N,144)
    const float* __restrict__ kpT2,  // (B,12,512,12)
    const float* __restrict__ p,     // (B,N,N,128)
    const float* __restrict__ wb,    // (128,12)
    const float* __restrict__ bpb,   // (12)
    const float* __restrict__ hwts,  // (12)
    const float* __restrict__ mask,  // (B,N)
    float* __restrict__ l)           // (B,12,512,512)
{
    __shared__ __align__(16) float q_s[192];
    __shared__ __align__(16) float qp_s[144];
    __shared__ float red[128 * 25];  // [j_local][q*12+h], stride 25 (no conflicts)
    __shared__ float hw_s[12];
    __shared__ float misc_s[2];

    const int bid = blockIdx.x;
    const int row = bid >> 2, jc = bid & 3;
    const int b = row >> 9, i = row & 511;
    const int j0 = jc * 128;
    const int t = threadIdx.x;
    const int cg = t & 31, jg = t >> 5;

    for (int idx = t; idx < 192; idx += 256) q_s[idx] = q_o[(size_t)row * 192 + idx];
    for (int idx = t; idx < 144; idx += 256) qp_s[idx] = qpg[(size_t)row * 144 + idx];
    if (t < 12) {
        float x = hwts[t];
        float sp = (x > 20.f) ? x : log1pf(__expf(x));
        hw_s[t] = sp * HW_COEF;
    }
    if (t == 0) misc_s[0] = mask[row];

    // wb -> registers: this thread's 4 c x 12 h
    float wbr[4][12];
    #pragma unroll
    for (int u = 0; u < 4; ++u)
        #pragma unroll
        for (int h = 0; h < 12; ++h)
            wbr[u][h] = wb[(cg * 4 + u) * 12 + h];

    const float* psrc = p + ((size_t)(b * 512 + i) * 512 + j0) * 128;
    float4 pv[4];
    #pragma unroll
    for (int u = 0; u < 4; ++u)
        pv[u] = *(const float4*)&psrc[(size_t)(jg * 16 + u) * 128 + cg * 4];
    __syncthreads();

    // p @ wb with window prefetch; full in-wave c-reduction
    for (int base = 0; base < 16; base += 4) {
        float4 nx[4];
        if (base < 12) {
            #pragma unroll
            for (int u = 0; u < 4; ++u)
                nx[u] = *(const float4*)&psrc[(size_t)(jg * 16 + base + 4 + u) * 128 + cg * 4];
        }
        #pragma unroll
        for (int u = 0; u < 4; ++u) {
            int jl = jg * 16 + base + u;
            float partial[12];
            #pragma unroll
            for (int h = 0; h < 12; ++h)
                partial[h] = pv[u].x * wbr[0][h] + pv[u].y * wbr[1][h]
                           + pv[u].z * wbr[2][h] + pv[u].w * wbr[3][h];
            #pragma unroll
            for (int h = 0; h < 12; ++h) {
                partial[h] += __shfl_xor(partial[h], 1, 64);
                partial[h] += __shfl_xor(partial[h], 2, 64);
                partial[h] += __shfl_xor(partial[h], 4, 64);
                partial[h] += __shfl_xor(partial[h], 8, 64);
            }
            if ((cg & 15) == 0) {
                #pragma unroll
                for (int h = 0; h < 12; ++h)
                    red[jl * 25 + (cg >> 4) * 12 + h] = partial[h];
            }
        }
        #pragma unroll
        for (int u = 0; u < 4; ++u) pv[u] = nx[u];
    }
    __syncthreads();

    // finish: qk + pt + bias + mask + BB*(p@wb); write l coalesced
    const float mi = misc_s[0];
    const float4* q4 = (const float4*)q_s;
    const float4* qp4 = (const float4*)qp_s;
    for (int idx = t; idx < 1536; idx += 256) {
        int h = idx >> 7, jl = idx & 127;
        int j = j0 + jl;
        float pwb = red[jl * 25 + h] + red[jl * 25 + 12 + h];
        const float4* k4 = (const float4*)&kT2[((size_t)((b * 12 + h) << 9) + j) * 16];
        float qk = 0.f;
        #pragma unroll
        for (int c4 = 0; c4 < 4; ++c4) {
            float4 qv = q4[h * 4 + c4], kv = k4[c4];
            qk += qv.x * kv.x + qv.y * kv.y + qv.z * kv.z + qv.w * kv.w;
        }
        const float4* kp4 = (const float4*)&kpT2[((size_t)((b * 12 + h) << 9) + j) * 12];
        float d2 = 0.f;
        #pragma unroll
        for (int x = 0; x < 3; ++x) {
            float4 qp = qp4[h * 3 + x], kp = kp4[x];
            float dx = qp.x - kp.x, dy = qp.y - kp.y;
            float dz = qp.z - kp.z, dw = qp.w - kp.w;
            d2 += dx * dx + dy * dy + dz * dz + dw * dw;
        }
        float mj = mask[b * 512 + j];
        l[((size_t)(b * 12 + h) * 512 + i) * 512 + j] =
            QK_SCALE * qk - 0.5f * hw_s[h] * d2
            + BB_SCALE * (bpb[h] + pwb) + 100000.0f * (mi * mj - 1.0f);
    }
}

// ---------------------------------------------------------------------------
// K_SOFTMAX: in-place softmax over last dim of l. One wave per (b,h,i) row.
// ---------------------------------------------------------------------------
__global__ __launch_bounds__(256) void k_softmax(float* __restrict__ l)
{
    const int gid = blockIdx.x * 4 + (threadIdx.x >> 6);
    const int lane = threadIdx.x & 63;
    float4* lr = (float4*)(l + (size_t)gid * 512);
    float4 v0 = lr[lane], v1 = lr[lane + 64];
    float m = fmaxf(fmaxf(fmaxf(v0.x, v0.y), fmaxf(v0.z, v0.w)),
                    fmaxf(fmaxf(v1.x, v1.y), fmaxf(v1.z, v1.w)));
    #pragma unroll
    for (int o = 32; o > 0; o >>= 1) m = fmaxf(m, __shfl_xor(m, o, 64));
    v0.x = __expf(v0.x - m); v0.y = __expf(v0.y - m);
    v0.z = __expf(v0.z - m); v0.w = __expf(v0.w - m);
    v1.x = __expf(v1.x - m); v1.y = __expf(v1.y - m);
    v1.z = __expf(v1.z - m); v1.w = __expf(v1.w - m);
    float ssum = v0.x + v0.y + v0.z + v0.w + v1.x + v1.y + v1.z + v1.w;
    #pragma unroll
    for (int o = 32; o > 0; o >>= 1) ssum += __shfl_xor(ssum, o, 64);
    float inv = 1.0f / ssum;
    v0.x *= inv; v0.y *= inv; v0.z *= inv; v0.w *= inv;
    v1.x *= inv; v1.y *= inv; v1.z *= inv; v1.w *= inv;
    lr[lane] = v0; lr[lane + 64] = v1;
}

// ---------------------------------------------------------------------------
// K_OPAIR: partial o_pair[h][c] over a 128-j chunk. Grid 4096 (reversed row
// order for L3 reuse of p). 256 threads; a chunk staged transposed in LDS.
// ---------------------------------------------------------------------------
__global__ __launch_bounds__(256, 4) void k_opair(
    const float* __restrict__ a,     // (B,12,512,512) normalized
    const float* __restrict__ p,     // (B,N,N,128)
    float* __restrict__ opart)       // (1024*4, 1536)
{
    __shared__ __align__(16) float a_s[128 * 16];  // [j][16] (12 used)
    __shared__ float red[256 * 25];                // 25.6KB, used twice
    const int bid = blockIdx.x;
    const int row = 1023 - (bid >> 2), jc = bid & 3;
    const int b = row >> 9, i = row & 511;
    const int j0 = jc * 128;
    const int t = threadIdx.x;
    const int cg = t & 31, jg = t >> 5;

    for (int idx = t; idx < 384; idx += 256) {
        int h = idx >> 5, c4 = idx & 31;
        float4 av = *(const float4*)&a[((size_t)(b * 12 + h) * 512 + i) * 512 + j0 + c4 * 4];
        a_s[(c4 * 4 + 0) * 16 + h] = av.x;
        a_s[(c4 * 4 + 1) * 16 + h] = av.y;
        a_s[(c4 * 4 + 2) * 16 + h] = av.z;
        a_s[(c4 * 4 + 3) * 16 + h] = av.w;
    }
    const float* psrc = p + ((size_t)(b * 512 + i) * 512 + j0) * 128;
    float4 pv[4];
    #pragma unroll
    for (int u = 0; u < 4; ++u)
        pv[u] = *(const float4*)&psrc[(size_t)(jg * 16 + u) * 128 + cg * 4];
    __syncthreads();

    float acc[12][4] = {};
    for (int base = 0; base < 16; base += 4) {
        float4 nx[4];
        if (base < 12) {
            #pragma unroll
            for (int u = 0; u < 4; ++u)
                nx[u] = *(const float4*)&psrc[(size_t)(jg * 16 + base + 4 + u) * 128 + cg * 4];
        }
        #pragma unroll
        for (int u = 0; u < 4; ++u) {
            int jl = jg * 16 + base + u;
            float4 a0 = *(const float4*)&a_s[jl * 16 + 0];
            float4 a1 = *(const float4*)&a_s[jl * 16 + 4];
            float4 a2 = *(const float4*)&a_s[jl * 16 + 8];
            acc[0][0] += a0.x * pv[u].x; acc[0][1] += a0.x * pv[u].y; acc[0][2] += a0.x * pv[u].z; acc[0][3] += a0.x * pv[u].w;
            acc[1][0] += a0.y * pv[u].x; acc[1][1] += a0.y * pv[u].y; acc[1][2] += a0.y * pv[u].z; acc[1][3] += a0.y * pv[u].w;
            acc[2][0] += a0.z * pv[u].x; acc[2][1] += a0.z * pv[u].y; acc[2][2] += a0.z * pv[u].z; acc[2][3] += a0.z * pv[u].w;
            acc[3][0] += a0.w * pv[u].x; acc[3][1] += a0.w * pv[u].y; acc[3][2] += a0.w * pv[u].z; acc[3][3] += a0.w * pv[u].w;
            acc[4][0] += a1.x * pv[u].x; acc[4][1] += a1.x * pv[u].y; acc[4][2] += a1.x * pv[u].z; acc[4][3] += a1.x * pv[u].w;
            acc[5][0] += a1.y * pv[u].x; acc[5][1] += a1.y * pv[u].y; acc[5][2] += a1.y * pv[u].z; acc[5][3] += a1.y * pv[u].w;
            acc[6][0] += a1.z * pv[u].x; acc[6][1] += a1.z * pv[u].y; acc[6][2] += a1.z * pv[u].z; acc[6][3] += a1.z * pv[u].w;
            acc[7][0] += a1.w * pv[u].x; acc[7][1] += a1.w * pv[u].y; acc[7][2] += a1.w * pv[u].z; acc[7][3] += a1.w * pv[u].w;
            acc[8][0] += a2.x * pv[u].x; acc[8][1] += a2.x * pv[u].y; acc[8][2] += a2.x * pv[u].z; acc[8][3] += a2.x * pv[u].w;
            acc[9][0] += a2.y * pv[u].x; acc[9][1] += a2.y * pv[u].y; acc[9][2] += a2.y * pv[u].z; acc[9][3] += a2.y * pv[u].w;
            acc[10][0] += a2.z * pv[u].x; acc[10][1] += a2.z * pv[u].y; acc[10][2] += a2.z * pv[u].z; acc[10][3] += a2.z * pv[u].w;
            acc[11][0] += a2.w * pv[u].x; acc[11][1] += a2.w * pv[u].y; acc[11][2] += a2.w * pv[u].z; acc[11][3] += a2.w * pv[u].w;
        }
        #pragma unroll
        for (int u = 0; u < 4; ++u) pv[u] = nx[u];
    }
    __syncthreads();

    const size_t ob = ((size_t)row * 4 + jc) * 1536;
    #pragma unroll
    for (int half = 0; half < 2; ++half) {
        #pragma unroll
        for (int h2 = 0; h2 < 6; ++h2)
            #pragma unroll
            for (int u = 0; u < 4; ++u)
                red[t * 25 + h2 * 4 + u] = acc[half * 6 + h2][u];
        __syncthreads();
        for (int idx = t; idx < 768; idx += 256) {
            int h2 = idx >> 7, c = idx & 127;
            int cg2 = c >> 2, u = c & 3;
            float sv = 0.f;
            #pragma unroll
            for (int q = 0; q < 8; ++q) sv += red[(q * 32 + cg2) * 25 + h2 * 4 + u];
            opart[ob + (half * 6 + h2) * 128 + c] = sv;
        }
        __syncthreads();
    }
}

// ---------------------------------------------------------------------------
// K_FINISH: sum o_pair partials; o = a@v, o_pt_g = a@v_pts; R^T epilogue.
// One block per row.
// ---------------------------------------------------------------------------
__global__ __launch_bounds__(256) void k_finish(
    const float* __restrict__ opart, const float* __restrict__ a,
    const float* __restrict__ vT, const float* __restrict__ vptsT,
    const float* __restrict__ t_rot, const float* __restrict__ t_trans,
    float* __restrict__ feats)
{
    __shared__ __align__(16) float optg_s[288];
    __shared__ float R_s[9], T_s[3];
    const int row = blockIdx.x;
    const int b = row >> 9, i = row & 511;
    const int t = threadIdx.x;
    if (t < 9) R_s[t] = t_rot[(size_t)row * 9 + t];
    if (t < 3) T_s[t] = t_trans[(size_t)row * 3 + t];

    size_t fb = (size_t)row * 2112;
    for (int idx = t; idx < 1536; idx += 256) {
        float sv = 0.f;
        #pragma unroll
        for (int q = 0; q < 4; ++q)
            sv += opart[((size_t)row * 4 + q) * 1536 + idx];
        feats[fb + 576 + idx] = sv;
    }

    const int w = t >> 6, lane = t & 63;
    for (int oi = w; oi < 480; oi += 4) {
        const float* src; int h;
        if (oi < 192) { h = oi >> 4; src = vT + ((size_t)((b * 12 + h) * 16 + (oi & 15)) << 9); }
        else { int o2 = oi - 192; h = o2 / 24; src = vptsT + ((size_t)((b * 12 + h) * 24 + (o2 % 24)) << 9); }
        const float4* s4 = (const float4*)src;
        const float4* a4 = (const float4*)&a[((size_t)(b * 12 + h) * 512 + i) * 512];
        float accv = 0.f;
        #pragma unroll
        for (int r2 = 0; r2 < 2; ++r2) {
            int jq = lane + r2 * 64;
            float4 av = a4[jq];
            float4 vv = s4[jq];
            accv += av.x * vv.x + av.y * vv.y + av.z * vv.z + av.w * vv.w;
        }
        #pragma unroll
        for (int o = 32; o > 0; o >>= 1) accv += __shfl_xor(accv, o, 64);
        if (lane == 0) {
            if (oi < 192) feats[fb + oi] = accv;
            else          optg_s[oi - 192] = accv;
        }
    }
    __syncthreads();

    if (t < 96) {
        float gx = optg_s[t * 3 + 0] - T_s[0];
        float gy = optg_s[t * 3 + 1] - T_s[1];
        float gz = optg_s[t * 3 + 2] - T_s[2];
        float ox = R_s[0] * gx + R_s[3] * gy + R_s[6] * gz;
        float oy = R_s[1] * gx + R_s[4] * gy + R_s[7] * gz;
        float oz = R_s[2] * gx + R_s[5] * gy + R_s[8] * gz;
        float nrm = sqrtf(ox * ox + oy * oy + oz * oz + 1e-8f);
        feats[fb + 192 + t] = ox;
        feats[fb + 288 + t] = oy;
        feats[fb + 384 + t] = oz;
        feats[fb + 480 + t] = nrm;
    }
}

// ---------------------------------------------------------------------------
// K_GEMM: tiled f32 GEMM, 32r x 128c per block, 4x4/thread, split-K via z.
// ---------------------------------------------------------------------------
__global__ __launch_bounds__(256) void k_gemm(
    const float* __restrict__ A0, const float* __restrict__ A1,
    const float* __restrict__ abias, int lda,
    const float* __restrict__ W,
    float* __restrict__ out, int k_chunks, int do_relu)
{
    __shared__ __align__(16) float A_t[64 * 36];
    __shared__ __align__(16) float W_s[64 * 132];
    const int row0 = blockIdx.x * 32;
    const int C0 = blockIdx.y * 128;
    const int k_base = blockIdx.z * k_chunks * 64;
    const int t = threadIdx.x;
    const int cq = t & 31, rq = t >> 5;
    float acc[4][4] = {};
    for (int ch = 0; ch < k_chunks; ++ch) {
        const int k0 = k_base + ch * 64;
        __syncthreads();
        for (int idx = t; idx < 512; idx += 256) {
            int r = idx & 31, kq = idx >> 5;
            float4 a = *(const float4*)&A0[(size_t)(row0 + r) * lda + k0 + kq * 4];
            if (A1) {
                float4 a1 = *(const float4*)&A1[(size_t)(row0 + r) * lda + k0 + kq * 4];
                a.x += a1.x; a.y += a1.y; a.z += a1.z; a.w += a1.w;
            }
            if (abias) {
                float4 ab = *(const float4*)&abias[k0 + kq * 4];
                a.x += ab.x; a.y += ab.y; a.z += ab.z; a.w += ab.w;
            }
            if (do_relu) {
                a.x = fmaxf(a.x, 0.f); a.y = fmaxf(a.y, 0.f);
                a.z = fmaxf(a.z, 0.f); a.w = fmaxf(a.w, 0.f);
            }
            A_t[(kq * 4 + 0) * 36 + r] = a.x;
            A_t[(kq * 4 + 1) * 36 + r] = a.y;
            A_t[(kq * 4 + 2) * 36 + r] = a.z;
            A_t[(kq * 4 + 3) * 36 + r] = a.w;
        }
        for (int idx = t; idx < 2048; idx += 256) {
            int kk = idx >> 5, c4 = idx & 31;
            *(float4*)&W_s[kk * 132 + c4 * 4] =
                *(const float4*)&W[(size_t)(k0 + kk) * 384 + C0 + c4 * 4];
        }
        __syncthreads();
        #pragma unroll 8
        for (int kk = 0; kk < 64; ++kk) {
            float4 a4 = *(const float4*)&A_t[kk * 36 + rq * 4];
            float4 w4 = *(const float4*)&W_s[kk * 132 + cq * 4];
            acc[0][0] += a4.x * w4.x; acc[0][1] += a4.x * w4.y; acc[0][2] += a4.x * w4.z; acc[0][3] += a4.x * w4.w;
            acc[1][0] += a4.y * w4.x; acc[1][1] += a4.y * w4.y; acc[1][2] += a4.y * w4.z; acc[1][3] += a4.y * w4.w;
            acc[2][0] += a4.z * w4.x; acc[2][1] += a4.z * w4.y; acc[2][2] += a4.z * w4.z; acc[2][3] += a4.z * w4.w;
            acc[3][0] += a4.w * w4.x; acc[3][1] += a4.w * w4.y; acc[3][2] += a4.w * w4.z; acc[3][3] += a4.w * w4.w;
        }
    }
    float* outp = out + (size_t)blockIdx.z * 393216;
    #pragma unroll
    for (int r = 0; r < 4; ++r) {
        float4 st = { acc[r][0], acc[r][1], acc[r][2], acc[r][3] };
        *(float4*)&outp[(size_t)(row0 + rq * 4 + r) * 384 + C0 + cq * 4] = st;
    }
}

// ---------------------------------------------------------------------------
// K_LNSUM: out = LN( sum(parts) + bias + resid ). One wave per row.
// ---------------------------------------------------------------------------
__global__ __launch_bounds__(256) void k_lnsum(
    const float* __restrict__ parts, int np,
    const float* __restrict__ bias, const float* __restrict__ resid,
    const float* __restrict__ g, const float* __restrict__ bta,
    float* __restrict__ o)
{
    const int wid = (blockIdx.x * 256 + threadIdx.x) >> 6;
    const int lane = threadIdx.x & 63;
    float v[6], sum = 0.f, sq = 0.f;
    #pragma unroll
    for (int u = 0; u < 6; ++u) {
        int c = lane + 64 * u;
        float x = bias[c] + resid[(size_t)wid * 384 + c];
        for (int q = 0; q < np; ++q)
            x += parts[(size_t)q * 393216 + (size_t)wid * 384 + c];
        v[u] = x; sum += x; sq += x * x;
    }
    #pragma unroll
    for (int off = 32; off > 0; off >>= 1) {
        sum += __shfl_xor(sum, off, 64);
        sq  += __shfl_xor(sq, off, 64);
    }
    float mean = sum * (1.f / 384.f);
    float var = sq * (1.f / 384.f) - mean * mean;
    float rst = rsqrtf(var + 1e-5f);
    #pragma unroll
    for (int u = 0; u < 6; ++u) {
        int c = lane + 64 * u;
        o[(size_t)wid * 384 + c] = (v[u] - mean) * rst * g[c] + bta[c];
    }
}

// ---------------------------------------------------------------------------
// K_BB: backbone update. One wave per row.
// ---------------------------------------------------------------------------
__global__ __launch_bounds__(256) void k_bb(
    const float* __restrict__ sfin, const float* __restrict__ w_bb,
    const float* __restrict__ b_bb,
    const float* __restrict__ t_rot, const float* __restrict__ t_trans,
    float* __restrict__ rot_out, float* __restrict__ trans_out)
{
    const int wid = (blockIdx.x * 256 + threadIdx.x) >> 6;
    const int lane = threadIdx.x & 63;
    const float* srow = sfin + (size_t)wid * 384;
    float u[6] = {0.f, 0.f, 0.f, 0.f, 0.f, 0.f};
    for (int k = lane; k < 384; k += 64) {
        float sv = srow[k];
        #pragma unroll
        for (int j = 0; j < 6; ++j) u[j] += sv * w_bb[k * 6 + j];
    }
    #pragma unroll
    for (int j = 0; j < 6; ++j) {
        #pragma unroll
        for (int o = 32; o > 0; o >>= 1) u[j] += __shfl_xor(u[j], o, 64);
    }
    if (lane == 0) {
        #pragma unroll
        for (int j = 0; j < 6; ++j) u[j] += b_bb[j];
        float bq = u[0], cq = u[1], dq = u[2];
        float inv = rsqrtf(1.f + bq * bq + cq * cq + dq * dq);
        float a = inv, bqn = bq * inv, cqn = cq * inv, dqn = dq * inv;
        float R[9];
        R[0] = a * a + bqn * bqn - cqn * cqn - dqn * dqn;
        R[1] = 2.f * (bqn * cqn - a * dqn);
        R[2] = 2.f * (bqn * dqn + a * cqn);
        R[3] = 2.f * (bqn * cqn + a * dqn);
        R[4] = a * a - bqn * bqn + cqn * cqn - dqn * dqn;
        R[5] = 2.f * (cqn * dqn - a * bqn);
        R[6] = 2.f * (bqn * dqn - a * cqn);
        R[7] = 2.f * (cqn * dqn + a * bqn);
        R[8] = a * a - bqn * bqn - cqn * cqn + dqn * dqn;
        const float* Rt = t_rot + (size_t)wid * 9;
        #pragma unroll
        for (int i2 = 0; i2 < 3; ++i2) {
            #pragma unroll
            for (int k2 = 0; k2 < 3; ++k2) {
                rot_out[(size_t)wid * 9 + i2 * 3 + k2] =
                    Rt[i2 * 3 + 0] * R[0 + k2] + Rt[i2 * 3 + 1] * R[3 + k2] + Rt[i2 * 3 + 2] * R[6 + k2];
            }
            trans_out[(size_t)wid * 3 + i2] =
                Rt[i2 * 3 + 0] * u[3] + Rt[i2 * 3 + 1] * u[4] + Rt[i2 * 3 + 2] * u[5]
                + t_trans[(size_t)wid * 3 + i2];
        }
    }
}

// ---------------------------------------------------------------------------
extern "C" void kernel_launch(void* const* d_in, const int* in_sizes, int n_in,
                              void* d_out, int out_size, void* d_ws, size_t ws_size,
                              hipStream_t stream) {
    const float* s      = (const float*)d_in[0];
    const float* p      = (const float*)d_in[1];
    const float* t_rot  = (const float*)d_in[2];
    const float* t_trans= (const float*)d_in[3];
    const float* mask   = (const float*)d_in[4];
    const float* wq     = (const float*)d_in[5];
    const float* bq     = (const float*)d_in[6];
    const float* wkv    = (const float*)d_in[7];
    const float* bkv    = (const float*)d_in[8];
    const float* wqp    = (const float*)d_in[9];
    const float* bqp    = (const float*)d_in[10];
    const float* wkvp   = (const float*)d_in[11];
    const float* bkvp   = (const float*)d_in[12];
    const float* wb     = (const float*)d_in[13];
    const float* bpb    = (const float*)d_in[14];
    const float* hwts   = (const float*)d_in[15];
    const float* w_out  = (const float*)d_in[16];
    const float* b_out  = (const float*)d_in[17];
    const float* ln1s   = (const float*)d_in[18];
    const float* ln1b   = (const float*)d_in[19];
    const float* wt1    = (const float*)d_in[20];
    const float* bt1    = (const float*)d_in[21];
    const float* wt2    = (const float*)d_in[22];
    const float* bt2    = (const float*)d_in[23];
    const float* wt3    = (const float*)d_in[24];
    const float* bt3    = (const float*)d_in[25];
    const float* ln2s   = (const float*)d_in[26];
    const float* ln2b   = (const float*)d_in[27];
    const float* w_bb   = (const float*)d_in[28];
    const float* b_bb   = (const float*)d_in[29];
    float* out = (float*)d_out;
    float* ws  = (float*)d_ws;

    float* q_o   = ws;                    // 196608
    float* kT2   = q_o   + 196608;        // 196608
    float* vT    = kT2   + 196608;        // 196608
    float* qpl   = vT    + 196608;        // 147456
    float* qpg   = qpl   + 147456;        // 147456
    float* kvpl  = qpg   + 147456;        // 442368
    float* kpT2  = kvpl  + 442368;        // 147456
    float* vptsT = kpT2  + 147456;        // 294912
    float* feats = vptsT + 294912;        // 2162688
    float* s1    = feats + 2162688;       // 393216
    float* g1p   = s1    + 393216;        // 3 x 393216
    float* h1p   = g1p   + 1179648;       // 2 x 393216
    float* h2p   = h1p   + 786432;        // 2 x 393216
    float* s2p   = h2p   + 786432;        // 2 x 393216
    float* l_buf = s2p   + 786432;        // 6291456 (25.2 MB)
    float* opart = l_buf + 6291456;       // 6291456 (25.2 MB)

    k_proj<<<dim3(32, 9), 256, 0, stream>>>(s, wq, bq, wkv, bkv, wqp, bqp, wkvp, bkvp,
                                            q_o, kT2, vT, qpl, kvpl);
    k_pts<<<1024, 192, 0, stream>>>(qpl, kvpl, t_rot, t_trans, qpg, kpT2, vptsT);
    k_logits<<<4096, 256, 0, stream>>>(q_o, kT2, qpg, kpT2, p, wb, bpb, hwts, mask, l_buf);
    k_softmax<<<3072, 256, 0, stream>>>(l_buf);
    k_opair<<<4096, 256, 0, stream>>>(l_buf, p, opart);
    k_finish<<<1024, 256, 0, stream>>>(opart, l_buf, vT, vptsT, t_rot, t_trans, feats);
    // out-proj: split-K 3 x 704
    k_gemm<<<dim3(32, 3, 3), 256, 0, stream>>>(feats, nullptr, nullptr, 2112,
                                               w_out, g1p, 11, 0);
    k_lnsum<<<256, 256, 0, stream>>>(g1p, 3, b_out, s, ln1s, ln1b, s1);
    k_gemm<<<dim3(32, 3, 2), 256, 0, stream>>>(s1, nullptr, nullptr, 384,
                                               wt1, h1p, 3, 0);
    k_gemm<<<dim3(32, 3, 2), 256, 0, stream>>>(h1p, h1p + 393216, bt1, 384,
                                               wt2, h2p, 3, 1);
    k_gemm<<<dim3(32, 3, 2), 256, 0, stream>>>(h2p, h2p + 393216, bt2, 384,
                                               wt3, s2p, 3, 1);
    k_lnsum<<<256, 256, 0, stream>>>(s2p, 2, bt3, s1, ln2s, ln2b, out);
    k_bb<<<256, 256, 0, stream>>>(out, w_bb, b_bb, t_rot, t_trans,
                                  out + 393216, out + 402432);
}

// Round 5
// 543.614 us; speedup vs baseline: 1.5671x; 1.5671x over previous
//
#include <hip/hip_runtime.h>
#include <math.h>

#define QK_SCALE 0.14433756729740643f   // 1/sqrt(3*16)
#define BB_SCALE 0.57735026918962576f   // 1/sqrt(3)
#define HW_COEF  0.13608276348795434f   // 1/sqrt(54)

// ---------------------------------------------------------------------------
// K_PROJ: tiled GEMM (1024x384)@(384x1152 composite) with scatter epilogue.
// ---------------------------------------------------------------------------
__global__ __launch_bounds__(256) void k_proj(
    const float* __restrict__ s,
    const float* __restrict__ wq,  const float* __restrict__ bq,
    const float* __restrict__ wkv, const float* __restrict__ bkv,
    const float* __restrict__ wqp, const float* __restrict__ bqp,
    const float* __restrict__ wkvp,const float* __restrict__ bkvp,
    float* __restrict__ q_o,    // (B,N,192)
    float* __restrict__ kT2,    // (B,12,512,16)
    float* __restrict__ vT,     // (B,12,16,512)
    float* __restrict__ qpl,    // (B,N,48,3) local
    float* __restrict__ kvpl)   // (B,N,144,3) local
{
    __shared__ __align__(16) float A_t[64 * 36];
    __shared__ __align__(16) float W_s[64 * 132];
    const int row0 = blockIdx.x * 32;
    const int C0 = blockIdx.y * 128;
    const int t = threadIdx.x;
    const int cq = t & 31, rq = t >> 5;
    float acc[4][4] = {};
    for (int ch = 0; ch < 6; ++ch) {
        const int k0 = ch * 64;
        __syncthreads();
        for (int idx = t; idx < 512; idx += 256) {
            int r = idx & 31, kq = idx >> 5;
            float4 a = *(const float4*)&s[(size_t)(row0 + r) * 384 + k0 + kq * 4];
            A_t[(kq * 4 + 0) * 36 + r] = a.x;
            A_t[(kq * 4 + 1) * 36 + r] = a.y;
            A_t[(kq * 4 + 2) * 36 + r] = a.z;
            A_t[(kq * 4 + 3) * 36 + r] = a.w;
        }
        for (int idx = t; idx < 2048; idx += 256) {
            int kk = idx >> 5, c4 = idx & 31;
            int C4 = C0 + c4 * 4;
            const float* w; int sub, wcols;
            if (C4 < 192)      { w = wq;   sub = C4;       wcols = 192; }
            else if (C4 < 576) { w = wkv;  sub = C4 - 192; wcols = 384; }
            else if (C4 < 720) { w = wqp;  sub = C4 - 576; wcols = 144; }
            else               { w = wkvp; sub = C4 - 720; wcols = 432; }
            *(float4*)&W_s[kk * 132 + c4 * 4] =
                *(const float4*)&w[(size_t)(k0 + kk) * wcols + sub];
        }
        __syncthreads();
        #pragma unroll 8
        for (int kk = 0; kk < 64; ++kk) {
            float4 a4 = *(const float4*)&A_t[kk * 36 + rq * 4];
            float4 w4 = *(const float4*)&W_s[kk * 132 + cq * 4];
            acc[0][0] += a4.x * w4.x; acc[0][1] += a4.x * w4.y; acc[0][2] += a4.x * w4.z; acc[0][3] += a4.x * w4.w;
            acc[1][0] += a4.y * w4.x; acc[1][1] += a4.y * w4.y; acc[1][2] += a4.y * w4.z; acc[1][3] += a4.y * w4.w;
            acc[2][0] += a4.z * w4.x; acc[2][1] += a4.z * w4.y; acc[2][2] += a4.z * w4.z; acc[2][3] += a4.z * w4.w;
            acc[3][0] += a4.w * w4.x; acc[3][1] += a4.w * w4.y; acc[3][2] += a4.w * w4.z; acc[3][3] += a4.w * w4.w;
        }
    }
    #pragma unroll
    for (int r = 0; r < 4; ++r) {
        int row = row0 + rq * 4 + r;
        int b = row >> 9, n = row & 511;
        #pragma unroll
        for (int u = 0; u < 4; ++u) {
            int col = C0 + cq * 4 + u;
            float v = acc[r][u];
            if (col < 192) {
                q_o[(size_t)row * 192 + col] = v + bq[col];
            } else if (col < 576) {
                int sub = col - 192;
                v += bkv[sub];
                int h = sub >> 5, rr = sub & 31;
                if (rr < 16) kT2[((size_t)((b * 12 + h) << 9) + n) * 16 + rr] = v;
                else         vT[(((b * 12 + h) * 16 + (rr - 16)) << 9) + n] = v;
            } else if (col < 720) {
                int sub = col - 576;
                v += bqp[sub];
                int axis = sub / 48, rem = sub % 48;
                qpl[(size_t)row * 144 + rem * 3 + axis] = v;
            } else {
                int sub = col - 720;
                v += bkvp[sub];
                int axis = sub / 144, rem = sub % 144;
                kvpl[(size_t)row * 432 + rem * 3 + axis] = v;
            }
        }
    }
}

// ---------------------------------------------------------------------------
// K_PTS: local->global point transform + scatter
// ---------------------------------------------------------------------------
__global__ __launch_bounds__(192) void k_pts(
    const float* __restrict__ qpl, const float* __restrict__ kvpl,
    const float* __restrict__ t_rot, const float* __restrict__ t_trans,
    float* __restrict__ qpg,    // (B,N,144)
    float* __restrict__ kpT2,   // (B,12,512,12)
    float* __restrict__ vptsT)  // (B,12,24,512)
{
    const int row = blockIdx.x;
    const int b = row >> 9, n = row & 511;
    const int t = threadIdx.x;
    __shared__ float R[9], T[3];
    if (t < 9) R[t] = t_rot[(size_t)row * 9 + t];
    if (t < 3) T[t] = t_trans[(size_t)row * 3 + t];
    __syncthreads();
    float lx, ly, lz;
    if (t < 48) {
        lx = qpl[(size_t)row * 144 + t * 3 + 0];
        ly = qpl[(size_t)row * 144 + t * 3 + 1];
        lz = qpl[(size_t)row * 144 + t * 3 + 2];
    } else {
        int pp = t - 48;
        lx = kvpl[(size_t)row * 432 + pp * 3 + 0];
        ly = kvpl[(size_t)row * 432 + pp * 3 + 1];
        lz = kvpl[(size_t)row * 432 + pp * 3 + 2];
    }
    float gx = R[0] * lx + R[1] * ly + R[2] * lz + T[0];
    float gy = R[3] * lx + R[4] * ly + R[5] * lz + T[1];
    float gz = R[6] * lx + R[7] * ly + R[8] * lz + T[2];
    if (t < 48) {
        qpg[(size_t)row * 144 + t * 3 + 0] = gx;
        qpg[(size_t)row * 144 + t * 3 + 1] = gy;
        qpg[(size_t)row * 144 + t * 3 + 2] = gz;
    } else {
        int pp = t - 48;
        int h = pp / 12, pt = pp % 12;
        if (pt < 4) {
            size_t base = ((size_t)((b * 12 + h) << 9) + n) * 12 + pt * 3;
            kpT2[base + 0] = gx; kpT2[base + 1] = gy; kpT2[base + 2] = gz;
        } else {
            int base = (((b * 12 + h) * 24 + (pt - 4) * 3) << 9) + n;
            vptsT[base] = gx; vptsT[base + 512] = gy; vptsT[base + 1024] = gz;
        }
    }
}

// ---------------------------------------------------------------------------
// K_LOGITS: l[b,h,i,j] = qk*scale + pt_att + BB*(bpb + p@wb) + mask.
// Grid = 4096 (row * 4 + jchunk). 256 threads. p streamed once, register
// window prefetch depth 4, p@wb reduced fully in-wave (xor 1,2,4,8).
// NOTE: no min-waves launch-bound — forcing 4/EU spilled acc/wbr to scratch
// (round 4: VGPR 64, 1.5 GB of spill traffic in the sibling kernel).
// ---------------------------------------------------------------------------
__global__ __launch_bounds__(256) void k_logits(
    const float* __restrict__ q_o,   // (B,N,192)
    const float* __restrict__ kT2,   // (B,12,512,16)
    const float* __restrict__ qpg,   // (B,N,144)
    const float* __restrict__ kpT2,  // (B,12,512,12)
    const float* __restrict__ p,     // (B,N,N,128)
    const float* __restrict__ wb,    // (128,12)
    const float* __restrict__ bpb,   // (12)
    const float* __restrict__ hwts,  // (12)
    const float* __restrict__ mask,  // (B,N)
    float* __restrict__ l)           // (B,12,512,512)
{
    __shared__ __align__(16) float q_s[192];
    __shared__ __align__(16) float qp_s[144];
    __shared__ float red[128 * 25];  // [j_local][q*12+h], stride 25 (no conflicts)
    __shared__ float hw_s[12];
    __shared__ float misc_s[2];

    const int bid = blockIdx.x;
    const int row = bid >> 2, jc = bid & 3;
    const int b = row >> 9, i = row & 511;
    const int j0 = jc * 128;
    const int t = threadIdx.x;
    const int cg = t & 31, jg = t >> 5;

    for (int idx = t; idx < 192; idx += 256) q_s[idx] = q_o[(size_t)row * 192 + idx];
    for (int idx = t; idx < 144; idx += 256) qp_s[idx] = qpg[(size_t)row * 144 + idx];
    if (t < 12) {
        float x = hwts[t];
        float sp = (x > 20.f) ? x : log1pf(__expf(x));
        hw_s[t] = sp * HW_COEF;
    }
    if (t == 0) misc_s[0] = mask[row];

    // wb -> registers: this thread's 4 c x 12 h
    float wbr[4][12];
    #pragma unroll
    for (int u = 0; u < 4; ++u)
        #pragma unroll
        for (int h = 0; h < 12; ++h)
            wbr[u][h] = wb[(cg * 4 + u) * 12 + h];

    const float* psrc = p + ((size_t)(b * 512 + i) * 512 + j0) * 128;
    float4 pv[4];
    #pragma unroll
    for (int u = 0; u < 4; ++u)
        pv[u] = *(const float4*)&psrc[(size_t)(jg * 16 + u) * 128 + cg * 4];
    __syncthreads();

    // p @ wb with window prefetch; full in-wave c-reduction
    for (int base = 0; base < 16; base += 4) {
        float4 nx[4];
        if (base < 12) {
            #pragma unroll
            for (int u = 0; u < 4; ++u)
                nx[u] = *(const float4*)&psrc[(size_t)(jg * 16 + base + 4 + u) * 128 + cg * 4];
        }
        #pragma unroll
        for (int u = 0; u < 4; ++u) {
            int jl = jg * 16 + base + u;
            float partial[12];
            #pragma unroll
            for (int h = 0; h < 12; ++h)
                partial[h] = pv[u].x * wbr[0][h] + pv[u].y * wbr[1][h]
                           + pv[u].z * wbr[2][h] + pv[u].w * wbr[3][h];
            #pragma unroll
            for (int h = 0; h < 12; ++h) {
                partial[h] += __shfl_xor(partial[h], 1, 64);
                partial[h] += __shfl_xor(partial[h], 2, 64);
                partial[h] += __shfl_xor(partial[h], 4, 64);
                partial[h] += __shfl_xor(partial[h], 8, 64);
            }
            if ((cg & 15) == 0) {
                #pragma unroll
                for (int h = 0; h < 12; ++h)
                    red[jl * 25 + (cg >> 4) * 12 + h] = partial[h];
            }
        }
        #pragma unroll
        for (int u = 0; u < 4; ++u) pv[u] = nx[u];
    }
    __syncthreads();

    // finish: qk + pt + bias + mask + BB*(p@wb); write l coalesced
    const float mi = misc_s[0];
    const float4* q4 = (const float4*)q_s;
    const float4* qp4 = (const float4*)qp_s;
    for (int idx = t; idx < 1536; idx += 256) {
        int h = idx >> 7, jl = idx & 127;
        int j = j0 + jl;
        float pwb = red[jl * 25 + h] + red[jl * 25 + 12 + h];
        const float4* k4 = (const float4*)&kT2[((size_t)((b * 12 + h) << 9) + j) * 16];
        float qk = 0.f;
        #pragma unroll
        for (int c4 = 0; c4 < 4; ++c4) {
            float4 qv = q4[h * 4 + c4], kv = k4[c4];
            qk += qv.x * kv.x + qv.y * kv.y + qv.z * kv.z + qv.w * kv.w;
        }
        const float4* kp4 = (const float4*)&kpT2[((size_t)((b * 12 + h) << 9) + j) * 12];
        float d2 = 0.f;
        #pragma unroll
        for (int x = 0; x < 3; ++x) {
            float4 qp = qp4[h * 3 + x], kp = kp4[x];
            float dx = qp.x - kp.x, dy = qp.y - kp.y;
            float dz = qp.z - kp.z, dw = qp.w - kp.w;
            d2 += dx * dx + dy * dy + dz * dz + dw * dw;
        }
        float mj = mask[b * 512 + j];
        l[((size_t)(b * 12 + h) * 512 + i) * 512 + j] =
            QK_SCALE * qk - 0.5f * hw_s[h] * d2
            + BB_SCALE * (bpb[h] + pwb) + 100000.0f * (mi * mj - 1.0f);
    }
}

// ---------------------------------------------------------------------------
// K_SOFTMAX: in-place softmax over last dim of l. One wave per (b,h,i) row.
// ---------------------------------------------------------------------------
__global__ __launch_bounds__(256) void k_softmax(float* __restrict__ l)
{
    const int gid = blockIdx.x * 4 + (threadIdx.x >> 6);
    const int lane = threadIdx.x & 63;
    float4* lr = (float4*)(l + (size_t)gid * 512);
    float4 v0 = lr[lane], v1 = lr[lane + 64];
    float m = fmaxf(fmaxf(fmaxf(v0.x, v0.y), fmaxf(v0.z, v0.w)),
                    fmaxf(fmaxf(v1.x, v1.y), fmaxf(v1.z, v1.w)));
    #pragma unroll
    for (int o = 32; o > 0; o >>= 1) m = fmaxf(m, __shfl_xor(m, o, 64));
    v0.x = __expf(v0.x - m); v0.y = __expf(v0.y - m);
    v0.z = __expf(v0.z - m); v0.w = __expf(v0.w - m);
    v1.x = __expf(v1.x - m); v1.y = __expf(v1.y - m);
    v1.z = __expf(v1.z - m); v1.w = __expf(v1.w - m);
    float ssum = v0.x + v0.y + v0.z + v0.w + v1.x + v1.y + v1.z + v1.w;
    #pragma unroll
    for (int o = 32; o > 0; o >>= 1) ssum += __shfl_xor(ssum, o, 64);
    float inv = 1.0f / ssum;
    v0.x *= inv; v0.y *= inv; v0.z *= inv; v0.w *= inv;
    v1.x *= inv; v1.y *= inv; v1.z *= inv; v1.w *= inv;
    lr[lane] = v0; lr[lane + 64] = v1;
}

// ---------------------------------------------------------------------------
// K_OPAIR: partial o_pair[h][c] over a 128-j chunk. Grid 4096 (reversed row
// order for L3 reuse of p). 256 threads; a chunk staged transposed in LDS.
// ---------------------------------------------------------------------------
__global__ __launch_bounds__(256) void k_opair(
    const float* __restrict__ a,     // (B,12,512,512) normalized
    const float* __restrict__ p,     // (B,N,N,128)
    float* __restrict__ opart)       // (1024*4, 1536)
{
    __shared__ __align__(16) float a_s[128 * 16];  // [j][16] (12 used)
    __shared__ float red[256 * 25];                // 25.6KB, used twice
    const int bid = blockIdx.x;
    const int row = 1023 - (bid >> 2), jc = bid & 3;
    const int b = row >> 9, i = row & 511;
    const int j0 = jc * 128;
    const int t = threadIdx.x;
    const int cg = t & 31, jg = t >> 5;

    for (int idx = t; idx < 384; idx += 256) {
        int h = idx >> 5, c4 = idx & 31;
        float4 av = *(const float4*)&a[((size_t)(b * 12 + h) * 512 + i) * 512 + j0 + c4 * 4];
        a_s[(c4 * 4 + 0) * 16 + h] = av.x;
        a_s[(c4 * 4 + 1) * 16 + h] = av.y;
        a_s[(c4 * 4 + 2) * 16 + h] = av.z;
        a_s[(c4 * 4 + 3) * 16 + h] = av.w;
    }
    const float* psrc = p + ((size_t)(b * 512 + i) * 512 + j0) * 128;
    float4 pv[4];
    #pragma unroll
    for (int u = 0; u < 4; ++u)
        pv[u] = *(const float4*)&psrc[(size_t)(jg * 16 + u) * 128 + cg * 4];
    __syncthreads();

    float acc[12][4] = {};
    for (int base = 0; base < 16; base += 4) {
        float4 nx[4];
        if (base < 12) {
            #pragma unroll
            for (int u = 0; u < 4; ++u)
                nx[u] = *(const float4*)&psrc[(size_t)(jg * 16 + base + 4 + u) * 128 + cg * 4];
        }
        #pragma unroll
        for (int u = 0; u < 4; ++u) {
            int jl = jg * 16 + base + u;
            float4 a0 = *(const float4*)&a_s[jl * 16 + 0];
            float4 a1 = *(const float4*)&a_s[jl * 16 + 4];
            float4 a2 = *(const float4*)&a_s[jl * 16 + 8];
            acc[0][0] += a0.x * pv[u].x; acc[0][1] += a0.x * pv[u].y; acc[0][2] += a0.x * pv[u].z; acc[0][3] += a0.x * pv[u].w;
            acc[1][0] += a0.y * pv[u].x; acc[1][1] += a0.y * pv[u].y; acc[1][2] += a0.y * pv[u].z; acc[1][3] += a0.y * pv[u].w;
            acc[2][0] += a0.z * pv[u].x; acc[2][1] += a0.z * pv[u].y; acc[2][2] += a0.z * pv[u].z; acc[2][3] += a0.z * pv[u].w;
            acc[3][0] += a0.w * pv[u].x; acc[3][1] += a0.w * pv[u].y; acc[3][2] += a0.w * pv[u].z; acc[3][3] += a0.w * pv[u].w;
            acc[4][0] += a1.x * pv[u].x; acc[4][1] += a1.x * pv[u].y; acc[4][2] += a1.x * pv[u].z; acc[4][3] += a1.x * pv[u].w;
            acc[5][0] += a1.y * pv[u].x; acc[5][1] += a1.y * pv[u].y; acc[5][2] += a1.y * pv[u].z; acc[5][3] += a1.y * pv[u].w;
            acc[6][0] += a1.z * pv[u].x; acc[6][1] += a1.z * pv[u].y; acc[6][2] += a1.z * pv[u].z; acc[6][3] += a1.z * pv[u].w;
            acc[7][0] += a1.w * pv[u].x; acc[7][1] += a1.w * pv[u].y; acc[7][2] += a1.w * pv[u].z; acc[7][3] += a1.w * pv[u].w;
            acc[8][0] += a2.x * pv[u].x; acc[8][1] += a2.x * pv[u].y; acc[8][2] += a2.x * pv[u].z; acc[8][3] += a2.x * pv[u].w;
            acc[9][0] += a2.y * pv[u].x; acc[9][1] += a2.y * pv[u].y; acc[9][2] += a2.y * pv[u].z; acc[9][3] += a2.y * pv[u].w;
            acc[10][0] += a2.z * pv[u].x; acc[10][1] += a2.z * pv[u].y; acc[10][2] += a2.z * pv[u].z; acc[10][3] += a2.z * pv[u].w;
            acc[11][0] += a2.w * pv[u].x; acc[11][1] += a2.w * pv[u].y; acc[11][2] += a2.w * pv[u].z; acc[11][3] += a2.w * pv[u].w;
        }
        #pragma unroll
        for (int u = 0; u < 4; ++u) pv[u] = nx[u];
    }
    __syncthreads();

    const size_t ob = ((size_t)row * 4 + jc) * 1536;
    #pragma unroll
    for (int half = 0; half < 2; ++half) {
        #pragma unroll
        for (int h2 = 0; h2 < 6; ++h2)
            #pragma unroll
            for (int u = 0; u < 4; ++u)
                red[t * 25 + h2 * 4 + u] = acc[half * 6 + h2][u];
        __syncthreads();
        for (int idx = t; idx < 768; idx += 256) {
            int h2 = idx >> 7, c = idx & 127;
            int cg2 = c >> 2, u = c & 3;
            float sv = 0.f;
            #pragma unroll
            for (int q = 0; q < 8; ++q) sv += red[(q * 32 + cg2) * 25 + h2 * 4 + u];
            opart[ob + (half * 6 + h2) * 128 + c] = sv;
        }
        __syncthreads();
    }
}

// ---------------------------------------------------------------------------
// K_FINISH: sum o_pair partials; o = a@v, o_pt_g = a@v_pts; R^T epilogue.
// One block per row.
// ---------------------------------------------------------------------------
__global__ __launch_bounds__(256) void k_finish(
    const float* __restrict__ opart, const float* __restrict__ a,
    const float* __restrict__ vT, const float* __restrict__ vptsT,
    const float* __restrict__ t_rot, const float* __restrict__ t_trans,
    float* __restrict__ feats)
{
    __shared__ __align__(16) float optg_s[288];
    __shared__ float R_s[9], T_s[3];
    const int row = blockIdx.x;
    const int b = row >> 9, i = row & 511;
    const int t = threadIdx.x;
    if (t < 9) R_s[t] = t_rot[(size_t)row * 9 + t];
    if (t < 3) T_s[t] = t_trans[(size_t)row * 3 + t];

    size_t fb = (size_t)row * 2112;
    for (int idx = t; idx < 1536; idx += 256) {
        float sv = 0.f;
        #pragma unroll
        for (int q = 0; q < 4; ++q)
            sv += opart[((size_t)row * 4 + q) * 1536 + idx];
        feats[fb + 576 + idx] = sv;
    }

    const int w = t >> 6, lane = t & 63;
    for (int oi = w; oi < 480; oi += 4) {
        const float* src; int h;
        if (oi < 192) { h = oi >> 4; src = vT + ((size_t)((b * 12 + h) * 16 + (oi & 15)) << 9); }
        else { int o2 = oi - 192; h = o2 / 24; src = vptsT + ((size_t)((b * 12 + h) * 24 + (o2 % 24)) << 9); }
        const float4* s4 = (const float4*)src;
        const float4* a4 = (const float4*)&a[((size_t)(b * 12 + h) * 512 + i) * 512];
        float accv = 0.f;
        #pragma unroll
        for (int r2 = 0; r2 < 2; ++r2) {
            int jq = lane + r2 * 64;
            float4 av = a4[jq];
            float4 vv = s4[jq];
            accv += av.x * vv.x + av.y * vv.y + av.z * vv.z + av.w * vv.w;
        }
        #pragma unroll
        for (int o = 32; o > 0; o >>= 1) accv += __shfl_xor(accv, o, 64);
        if (lane == 0) {
            if (oi < 192) feats[fb + oi] = accv;
            else          optg_s[oi - 192] = accv;
        }
    }
    __syncthreads();

    if (t < 96) {
        float gx = optg_s[t * 3 + 0] - T_s[0];
        float gy = optg_s[t * 3 + 1] - T_s[1];
        float gz = optg_s[t * 3 + 2] - T_s[2];
        float ox = R_s[0] * gx + R_s[3] * gy + R_s[6] * gz;
        float oy = R_s[1] * gx + R_s[4] * gy + R_s[7] * gz;
        float oz = R_s[2] * gx + R_s[5] * gy + R_s[8] * gz;
        float nrm = sqrtf(ox * ox + oy * oy + oz * oz + 1e-8f);
        feats[fb + 192 + t] = ox;
        feats[fb + 288 + t] = oy;
        feats[fb + 384 + t] = oz;
        feats[fb + 480 + t] = nrm;
    }
}

// ---------------------------------------------------------------------------
// K_GEMM: tiled f32 GEMM, 32r x 128c per block, 4x4/thread, split-K via z.
// ---------------------------------------------------------------------------
__global__ __launch_bounds__(256) void k_gemm(
    const float* __restrict__ A0, const float* __restrict__ A1,
    const float* __restrict__ abias, int lda,
    const float* __restrict__ W,
    float* __restrict__ out, int k_chunks, int do_relu)
{
    __shared__ __align__(16) float A_t[64 * 36];
    __shared__ __align__(16) float W_s[64 * 132];
    const int row0 = blockIdx.x * 32;
    const int C0 = blockIdx.y * 128;
    const int k_base = blockIdx.z * k_chunks * 64;
    const int t = threadIdx.x;
    const int cq = t & 31, rq = t >> 5;
    float acc[4][4] = {};
    for (int ch = 0; ch < k_chunks; ++ch) {
        const int k0 = k_base + ch * 64;
        __syncthreads();
        for (int idx = t; idx < 512; idx += 256) {
            int r = idx & 31, kq = idx >> 5;
            float4 a = *(const float4*)&A0[(size_t)(row0 + r) * lda + k0 + kq * 4];
            if (A1) {
                float4 a1 = *(const float4*)&A1[(size_t)(row0 + r) * lda + k0 + kq * 4];
                a.x += a1.x; a.y += a1.y; a.z += a1.z; a.w += a1.w;
            }
            if (abias) {
                float4 ab = *(const float4*)&abias[k0 + kq * 4];
                a.x += ab.x; a.y += ab.y; a.z += ab.z; a.w += ab.w;
            }
            if (do_relu) {
                a.x = fmaxf(a.x, 0.f); a.y = fmaxf(a.y, 0.f);
                a.z = fmaxf(a.z, 0.f); a.w = fmaxf(a.w, 0.f);
            }
            A_t[(kq * 4 + 0) * 36 + r] = a.x;
            A_t[(kq * 4 + 1) * 36 + r] = a.y;
            A_t[(kq * 4 + 2) * 36 + r] = a.z;
            A_t[(kq * 4 + 3) * 36 + r] = a.w;
        }
        for (int idx = t; idx < 2048; idx += 256) {
            int kk = idx >> 5, c4 = idx & 31;
            *(float4*)&W_s[kk * 132 + c4 * 4] =
                *(const float4*)&W[(size_t)(k0 + kk) * 384 + C0 + c4 * 4];
        }
        __syncthreads();
        #pragma unroll 8
        for (int kk = 0; kk < 64; ++kk) {
            float4 a4 = *(const float4*)&A_t[kk * 36 + rq * 4];
            float4 w4 = *(const float4*)&W_s[kk * 132 + cq * 4];
            acc[0][0] += a4.x * w4.x; acc[0][1] += a4.x * w4.y; acc[0][2] += a4.x * w4.z; acc[0][3] += a4.x * w4.w;
            acc[1][0] += a4.y * w4.x; acc[1][1] += a4.y * w4.y; acc[1][2] += a4.y * w4.z; acc[1][3] += a4.y * w4.w;
            acc[2][0] += a4.z * w4.x; acc[2][1] += a4.z * w4.y; acc[2][2] += a4.z * w4.z; acc[2][3] += a4.z * w4.w;
            acc[3][0] += a4.w * w4.x; acc[3][1] += a4.w * w4.y; acc[3][2] += a4.w * w4.z; acc[3][3] += a4.w * w4.w;
        }
    }
    float* outp = out + (size_t)blockIdx.z * 393216;
    #pragma unroll
    for (int r = 0; r < 4; ++r) {
        float4 st = { acc[r][0], acc[r][1], acc[r][2], acc[r][3] };
        *(float4*)&outp[(size_t)(row0 + rq * 4 + r) * 384 + C0 + cq * 4] = st;
    }
}

// ---------------------------------------------------------------------------
// K_LNSUM: out = LN( sum(parts) + bias + resid ). One wave per row.
// ---------------------------------------------------------------------------
__global__ __launch_bounds__(256) void k_lnsum(
    const float* __restrict__ parts, int np,
    const float* __restrict__ bias, const float* __restrict__ resid,
    const float* __restrict__ g, const float* __restrict__ bta,
    float* __restrict__ o)
{
    const int wid = (blockIdx.x * 256 + threadIdx.x) >> 6;
    const int lane = threadIdx.x & 63;
    float v[6], sum = 0.f, sq = 0.f;
    #pragma unroll
    for (int u = 0; u < 6; ++u) {
        int c = lane + 64 * u;
        float x = bias[c] + resid[(size_t)wid * 384 + c];
        for (int q = 0; q < np; ++q)
            x += parts[(size_t)q * 393216 + (size_t)wid * 384 + c];
        v[u] = x; sum += x; sq += x * x;
    }
    #pragma unroll
    for (int off = 32; off > 0; off >>= 1) {
        sum += __shfl_xor(sum, off, 64);
        sq  += __shfl_xor(sq, off, 64);
    }
    float mean = sum * (1.f / 384.f);
    float var = sq * (1.f / 384.f) - mean * mean;
    float rst = rsqrtf(var + 1e-5f);
    #pragma unroll
    for (int u = 0; u < 6; ++u) {
        int c = lane + 64 * u;
        o[(size_t)wid * 384 + c] = (v[u] - mean) * rst * g[c] + bta[c];
    }
}

// ---------------------------------------------------------------------------
// K_BB: backbone update. One wave per row.
// ---------------------------------------------------------------------------
__global__ __launch_bounds__(256) void k_bb(
    const float* __restrict__ sfin, const float* __restrict__ w_bb,
    const float* __restrict__ b_bb,
    const float* __restrict__ t_rot, const float* __restrict__ t_trans,
    float* __restrict__ rot_out, float* __restrict__ trans_out)
{
    const int wid = (blockIdx.x * 256 + threadIdx.x) >> 6;
    const int lane = threadIdx.x & 63;
    const float* srow = sfin + (size_t)wid * 384;
    float u[6] = {0.f, 0.f, 0.f, 0.f, 0.f, 0.f};
    for (int k = lane; k < 384; k += 64) {
        float sv = srow[k];
        #pragma unroll
        for (int j = 0; j < 6; ++j) u[j] += sv * w_bb[k * 6 + j];
    }
    #pragma unroll
    for (int j = 0; j < 6; ++j) {
        #pragma unroll
        for (int o = 32; o > 0; o >>= 1) u[j] += __shfl_xor(u[j], o, 64);
    }
    if (lane == 0) {
        #pragma unroll
        for (int j = 0; j < 6; ++j) u[j] += b_bb[j];
        float bq = u[0], cq = u[1], dq = u[2];
        float inv = rsqrtf(1.f + bq * bq + cq * cq + dq * dq);
        float a = inv, bqn = bq * inv, cqn = cq * inv, dqn = dq * inv;
        float R[9];
        R[0] = a * a + bqn * bqn - cqn * cqn - dqn * dqn;
        R[1] = 2.f * (bqn * cqn - a * dqn);
        R[2] = 2.f * (bqn * dqn + a * cqn);
        R[3] = 2.f * (bqn * cqn + a * dqn);
        R[4] = a * a - bqn * bqn + cqn * cqn - dqn * dqn;
        R[5] = 2.f * (cqn * dqn - a * bqn);
        R[6] = 2.f * (bqn * dqn - a * cqn);
        R[7] = 2.f * (cqn * dqn + a * bqn);
        R[8] = a * a - bqn * bqn - cqn * cqn + dqn * dqn;
        const float* Rt = t_rot + (size_t)wid * 9;
        #pragma unroll
        for (int i2 = 0; i2 < 3; ++i2) {
            #pragma unroll
            for (int k2 = 0; k2 < 3; ++k2) {
                rot_out[(size_t)wid * 9 + i2 * 3 + k2] =
                    Rt[i2 * 3 + 0] * R[0 + k2] + Rt[i2 * 3 + 1] * R[3 + k2] + Rt[i2 * 3 + 2] * R[6 + k2];
            }
            trans_out[(size_t)wid * 3 + i2] =
                Rt[i2 * 3 + 0] * u[3] + Rt[i2 * 3 + 1] * u[4] + Rt[i2 * 3 + 2] * u[5]
                + t_trans[(size_t)wid * 3 + i2];
        }
    }
}

// ---------------------------------------------------------------------------
extern "C" void kernel_launch(void* const* d_in, const int* in_sizes, int n_in,
                              void* d_out, int out_size, void* d_ws, size_t ws_size,
                              hipStream_t stream) {
    const float* s      = (const float*)d_in[0];
    const float* p      = (const float*)d_in[1];
    const float* t_rot  = (const float*)d_in[2];
    const float* t_trans= (const float*)d_in[3];
    const float* mask   = (const float*)d_in[4];
    const float* wq     = (const float*)d_in[5];
    const float* bq     = (const float*)d_in[6];
    const float* wkv    = (const float*)d_in[7];
    const float* bkv    = (const float*)d_in[8];
    const float* wqp    = (const float*)d_in[9];
    const float* bqp    = (const float*)d_in[10];
    const float* wkvp   = (const float*)d_in[11];
    const float* bkvp   = (const float*)d_in[12];
    const float* wb     = (const float*)d_in[13];
    const float* bpb    = (const float*)d_in[14];
    const float* hwts   = (const float*)d_in[15];
    const float* w_out  = (const float*)d_in[16];
    const float* b_out  = (const float*)d_in[17];
    const float* ln1s   = (const float*)d_in[18];
    const float* ln1b   = (const float*)d_in[19];
    const float* wt1    = (const float*)d_in[20];
    const float* bt1    = (const float*)d_in[21];
    const float* wt2    = (const float*)d_in[22];
    const float* bt2    = (const float*)d_in[23];
    const float* wt3    = (const float*)d_in[24];
    const float* bt3    = (const float*)d_in[25];
    const float* ln2s   = (const float*)d_in[26];
    const float* ln2b   = (const float*)d_in[27];
    const float* w_bb   = (const float*)d_in[28];
    const float* b_bb   = (const float*)d_in[29];
    float* out = (float*)d_out;
    float* ws  = (float*)d_ws;

    float* q_o   = ws;                    // 196608
    float* kT2   = q_o   + 196608;        // 196608
    float* vT    = kT2   + 196608;        // 196608
    float* qpl   = vT    + 196608;        // 147456
    float* qpg   = qpl   + 147456;        // 147456
    float* kvpl  = qpg   + 147456;        // 442368
    float* kpT2  = kvpl  + 442368;        // 147456
    float* vptsT = kpT2  + 147456;        // 294912
    float* feats = vptsT + 294912;        // 2162688
    float* s1    = feats + 2162688;       // 393216
    float* g1p   = s1    + 393216;        // 3 x 393216
    float* h1p   = g1p   + 1179648;       // 2 x 393216
    float* h2p   = h1p   + 786432;        // 2 x 393216
    float* s2p   = h2p   + 786432;        // 2 x 393216
    float* l_buf = s2p   + 786432;        // 6291456 (25.2 MB)
    float* opart = l_buf + 6291456;       // 6291456 (25.2 MB)

    k_proj<<<dim3(32, 9), 256, 0, stream>>>(s, wq, bq, wkv, bkv, wqp, bqp, wkvp, bkvp,
                                            q_o, kT2, vT, qpl, kvpl);
    k_pts<<<1024, 192, 0, stream>>>(qpl, kvpl, t_rot, t_trans, qpg, kpT2, vptsT);
    k_logits<<<4096, 256, 0, stream>>>(q_o, kT2, qpg, kpT2, p, wb, bpb, hwts, mask, l_buf);
    k_softmax<<<3072, 256, 0, stream>>>(l_buf);
    k_opair<<<4096, 256, 0, stream>>>(l_buf, p, opart);
    k_finish<<<1024, 256, 0, stream>>>(opart, l_buf, vT, vptsT, t_rot, t_trans, feats);
    // out-proj: split-K 3 x 704
    k_gemm<<<dim3(32, 3, 3), 256, 0, stream>>>(feats, nullptr, nullptr, 2112,
                                               w_out, g1p, 11, 0);
    k_lnsum<<<256, 256, 0, stream>>>(g1p, 3, b_out, s, ln1s, ln1b, s1);
    k_gemm<<<dim3(32, 3, 2), 256, 0, stream>>>(s1, nullptr, nullptr, 384,
                                               wt1, h1p, 3, 0);
    k_gemm<<<dim3(32, 3, 2), 256, 0, stream>>>(h1p, h1p + 393216, bt1, 384,
                                               wt2, h2p, 3, 1);
    k_gemm<<<dim3(32, 3, 2), 256, 0, stream>>>(h2p, h2p + 393216, bt2, 384,
                                               wt3, s2p, 3, 1);
    k_lnsum<<<256, 256, 0, stream>>>(s2p, 2, bt3, s1, ln2s, ln2b, out);
    k_bb<<<256, 256, 0, stream>>>(out, w_bb, b_bb, t_rot, t_trans,
                                  out + 393216, out + 402432);
}